// Round 4
// baseline (277.014 us; speedup 1.0000x reference)
//
#include <hip/hip_runtime.h>
#include <math.h>

// Problem constants
#define Bsz 64
#define IC  512   // in_caps
#define KD  128   // in_dim
#define NC  32    // num_caps
#define DC  32    // dim_caps
#define CHUNK 64  // in_caps per sub-chunk
#define NCH   8   // IC / CHUNK
#define GBLK  256 // grid blocks (<= CU count: co-residency for sw barrier)
#define NTHR  256

#define CSTR 36   // padded stride for c_sT / wv_sT rows (floats); 144B, 16B-aligned
#define BSTR 68   // padded stride for bb_s rows
#define WSTR 33   // padded stride for w_s rows: bank=(k+d)%32 conflict-free

// workspace layout (floats)
#define CXP_SZ (Bsz * NCH * NC * KD)   // 8 MB   cx partials [b][ch][n][k]
#define WV_SZ  (Bsz * NC * KD)         // 1 MB   wv [b][n][k]
#define BB_SZ  (Bsz * NC * IC)         // 4 MB   bb after iter-1 update

// x_s: row i holds k-quads rotated by (i>>2)
__device__ __forceinline__ int xaddr(int i, int kq) {
    return i * KD + ((((kq) + (i >> 2)) & 31) << 2);
}

// software grid barrier: arrive (device-scope RMW) + bounded atomic-load spin.
// __threadfence() at agent scope emits the cross-XCD L2 writeback/invalidate on gfx950.
__device__ __forceinline__ void gridbar(unsigned* ctr, int slot) {
    __syncthreads();
    if (threadIdx.x == 0) {
        __threadfence();
        unsigned* c = ctr + slot;
        __hip_atomic_fetch_add(c, 1u, __ATOMIC_ACQ_REL, __HIP_MEMORY_SCOPE_AGENT);
        unsigned tries = 0;
        while (__hip_atomic_load(c, __ATOMIC_ACQUIRE, __HIP_MEMORY_SCOPE_AGENT) < GBLK &&
               tries < (1u << 20)) {
            ++tries;
            __builtin_amdgcn_s_sleep(4);
        }
        __threadfence();
    }
    __syncthreads();
}

__global__ __launch_bounds__(NTHR, 1)
void capsAll(const float* __restrict__ x_g, const float* __restrict__ W_g,
             const float* __restrict__ b0_g, float* __restrict__ out_g,
             float* __restrict__ cxp, float* __restrict__ wv_g,
             float* __restrict__ bb_ws, unsigned* __restrict__ ctr)
{
    __shared__ float x_s[CHUNK * KD];      // 32 KB (phase B aliases: cxs, vs_s)
    __shared__ float bb_s[NC * BSTR];      // 8.5 KB
    __shared__ float scr[KD * CSTR];       // 18 KB: wv_sT / c_sT / w_s

    const int t = threadIdx.x, blk = blockIdx.x;
    // ACX mapping: block owns batch b and chunk-pair {2*chpair, 2*chpair+1}
    const int b = blk >> 2, chpair = blk & 3;
    // B mapping: block owns capsule pb_n for 8 batches starting at pb_b0
    const int pb_n = blk & 31, pb_b0 = (blk >> 5) * 8;

    float* cxs  = x_s;            // [8][128]  (phase B)
    float* vs_s = x_s + 1024;     // [8][32]   (phase B)
    float* w_s  = scr;            // [128][33] (phase B)

    int slot = 0;
    for (int r = 0; r < 3; ++r) {
        const float* bb_in = (r <= 1) ? b0_g : bb_ws;
        const int do_uv = (r > 0), write_bb = (r == 1), final_ = (r == 2);

        // ---------- ACX passes: [uv + bb update] + softmax + cx partials ----------
        for (int sub = 0; sub < 2; ++sub) {
            const int ch = chpair * 2 + sub, i0g = ch * CHUNK;
            __syncthreads();   // protect x_s/scr/bb_s reuse from previous phase

            for (int rep = 0; rep < 8; ++rep) {
                int v = t + rep * NTHR;            // float4 idx 0..2047
                int i = v >> 5, kq = v & 31;
                *(float4*)(x_s + xaddr(i, kq)) =
                    *(const float4*)(x_g + ((size_t)(b * IC + i0g + i)) * KD + (kq << 2));
            }
            for (int rep = 0; rep < 2; ++rep) {
                int v = t + rep * NTHR;            // 0..511
                int n = v >> 4, i4 = v & 15;
                *(float4*)(bb_s + n * BSTR + (i4 << 2)) =
                    *(const float4*)(bb_in + ((size_t)(b * NC + n)) * IC + i0g + (i4 << 2));
            }
            if (do_uv) {
                for (int rep = 0; rep < 4; ++rep) {
                    const int n = t & 31;
                    const int k4 = (t >> 5) + (rep << 3);   // 0..31
                    float4 v4 = *(const float4*)(wv_g + ((size_t)(b * NC) + n) * KD + (k4 << 2));
                    scr[(k4 * 4 + 0) * CSTR + n] = v4.x;
                    scr[(k4 * 4 + 1) * CSTR + n] = v4.y;
                    scr[(k4 * 4 + 2) * CSTR + n] = v4.z;
                    scr[(k4 * 4 + 3) * CSTR + n] = v4.w;
                }
            }
            __syncthreads();

            if (do_uv) {
                if (t < 128) {
                    const int tn = t & 7, ti = t >> 3;
                    const int n0 = tn << 2, i0 = ti << 2;
                    float4 a0 = {0,0,0,0}, a1 = {0,0,0,0}, a2 = {0,0,0,0}, a3 = {0,0,0,0};
                    for (int kq = 0; kq < 32; ++kq) {
                        const float4 xr0 = *(const float4*)(x_s + xaddr(i0 + 0, kq));
                        const float4 xr1 = *(const float4*)(x_s + xaddr(i0 + 1, kq));
                        const float4 xr2 = *(const float4*)(x_s + xaddr(i0 + 2, kq));
                        const float4 xr3 = *(const float4*)(x_s + xaddr(i0 + 3, kq));
                        const float4 w0 = *(const float4*)(scr + (kq * 4 + 0) * CSTR + n0);
                        const float4 w1 = *(const float4*)(scr + (kq * 4 + 1) * CSTR + n0);
                        const float4 w2 = *(const float4*)(scr + (kq * 4 + 2) * CSTR + n0);
                        const float4 w3 = *(const float4*)(scr + (kq * 4 + 3) * CSTR + n0);
                        a0.x += xr0.x*w0.x + xr0.y*w1.x + xr0.z*w2.x + xr0.w*w3.x;
                        a0.y += xr0.x*w0.y + xr0.y*w1.y + xr0.z*w2.y + xr0.w*w3.y;
                        a0.z += xr0.x*w0.z + xr0.y*w1.z + xr0.z*w2.z + xr0.w*w3.z;
                        a0.w += xr0.x*w0.w + xr0.y*w1.w + xr0.z*w2.w + xr0.w*w3.w;
                        a1.x += xr1.x*w0.x + xr1.y*w1.x + xr1.z*w2.x + xr1.w*w3.x;
                        a1.y += xr1.x*w0.y + xr1.y*w1.y + xr1.z*w2.y + xr1.w*w3.y;
                        a1.z += xr1.x*w0.z + xr1.y*w1.z + xr1.z*w2.z + xr1.w*w3.z;
                        a1.w += xr1.x*w0.w + xr1.y*w1.w + xr1.z*w2.w + xr1.w*w3.w;
                        a2.x += xr2.x*w0.x + xr2.y*w1.x + xr2.z*w2.x + xr2.w*w3.x;
                        a2.y += xr2.x*w0.y + xr2.y*w1.y + xr2.z*w2.y + xr2.w*w3.y;
                        a2.z += xr2.x*w0.z + xr2.y*w1.z + xr2.z*w2.z + xr2.w*w3.z;
                        a2.w += xr2.x*w0.w + xr2.y*w1.w + xr2.z*w2.w + xr2.w*w3.w;
                        a3.x += xr3.x*w0.x + xr3.y*w1.x + xr3.z*w2.x + xr3.w*w3.x;
                        a3.y += xr3.x*w0.y + xr3.y*w1.y + xr3.z*w2.y + xr3.w*w3.y;
                        a3.z += xr3.x*w0.z + xr3.y*w1.z + xr3.z*w2.z + xr3.w*w3.z;
                        a3.w += xr3.x*w0.w + xr3.y*w1.w + xr3.z*w2.w + xr3.w*w3.w;
                    }
                    bb_s[(n0+0)*BSTR + i0+0] += a0.x; bb_s[(n0+1)*BSTR + i0+0] += a0.y;
                    bb_s[(n0+2)*BSTR + i0+0] += a0.z; bb_s[(n0+3)*BSTR + i0+0] += a0.w;
                    bb_s[(n0+0)*BSTR + i0+1] += a1.x; bb_s[(n0+1)*BSTR + i0+1] += a1.y;
                    bb_s[(n0+2)*BSTR + i0+1] += a1.z; bb_s[(n0+3)*BSTR + i0+1] += a1.w;
                    bb_s[(n0+0)*BSTR + i0+2] += a2.x; bb_s[(n0+1)*BSTR + i0+2] += a2.y;
                    bb_s[(n0+2)*BSTR + i0+2] += a2.z; bb_s[(n0+3)*BSTR + i0+2] += a2.w;
                    bb_s[(n0+0)*BSTR + i0+3] += a3.x; bb_s[(n0+1)*BSTR + i0+3] += a3.y;
                    bb_s[(n0+2)*BSTR + i0+3] += a3.z; bb_s[(n0+3)*BSTR + i0+3] += a3.w;
                }
                __syncthreads();
                if (write_bb) {
                    for (int rep = 0; rep < 2; ++rep) {
                        int v = t + rep * NTHR;
                        int n = v >> 4, i4 = v & 15;
                        *(float4*)(bb_ws + ((size_t)(b * NC + n)) * IC + i0g + (i4 << 2)) =
                            *(const float4*)(bb_s + n * BSTR + (i4 << 2));
                    }
                }
            }

            // softmax over n; write c^T into scr
            if (t < CHUNK) {
                const int ii = t;
                float m = -1e30f;
                #pragma unroll
                for (int n = 0; n < NC; ++n) m = fmaxf(m, bb_s[n * BSTR + ii]);
                float e[NC]; float sum = 0.f;
                #pragma unroll
                for (int n = 0; n < NC; ++n) { float ev = __expf(bb_s[n * BSTR + ii] - m); e[n] = ev; sum += ev; }
                const float inv = 1.f / sum;
                float* crow = scr + ii * CSTR;
                #pragma unroll
                for (int n = 0; n < NC; ++n) crow[n] = e[n] * inv;
            }
            __syncthreads();

            // cx = C @ X; each thread 4n x 4k
            {
                const int tn = t & 7, tk = t >> 3;
                const int n0 = tn << 2;
                float4 acc0 = {0,0,0,0}, acc1 = {0,0,0,0}, acc2 = {0,0,0,0}, acc3 = {0,0,0,0};
                for (int ii = 0; ii < CHUNK; ++ii) {
                    const float4 c4 = *(const float4*)(scr + ii * CSTR + n0);
                    const float4 x4 = *(const float4*)(x_s + xaddr(ii, tk));
                    acc0.x += c4.x*x4.x; acc0.y += c4.x*x4.y; acc0.z += c4.x*x4.z; acc0.w += c4.x*x4.w;
                    acc1.x += c4.y*x4.x; acc1.y += c4.y*x4.y; acc1.z += c4.y*x4.z; acc1.w += c4.y*x4.w;
                    acc2.x += c4.z*x4.x; acc2.y += c4.z*x4.y; acc2.z += c4.z*x4.z; acc2.w += c4.z*x4.w;
                    acc3.x += c4.w*x4.x; acc3.y += c4.w*x4.y; acc3.z += c4.w*x4.z; acc3.w += c4.w*x4.w;
                }
                float* base = cxp + ((size_t)(b * NCH + ch)) * NC * KD + (tk << 2);
                *(float4*)(base + (size_t)(n0 + 0) * KD) = acc0;
                *(float4*)(base + (size_t)(n0 + 1) * KD) = acc1;
                *(float4*)(base + (size_t)(n0 + 2) * KD) = acc2;
                *(float4*)(base + (size_t)(n0 + 3) * KD) = acc3;
            }
        }

        gridbar(ctr, slot++);   // cx partials visible

        // ---------- phase B: reduce partials, s = cx@W, squash, wv/out ----------
        {
            // stage W[pb_n] padded (scalar stores)
            for (int rep = 0; rep < 4; ++rep) {
                int v = t + rep * NTHR;            // 0..1023
                int k = v >> 3, d0 = (v & 7) << 2;
                float4 w4 = *(const float4*)(W_g + (size_t)pb_n * KD * DC + (v << 2));
                float* dst = w_s + k * WSTR + d0;
                dst[0] = w4.x; dst[1] = w4.y; dst[2] = w4.z; dst[3] = w4.w;
            }
            // reduce cx partials: thread = (bsub 0..7, k4 0..31)
            {
                const int bsub = t >> 5, k4 = t & 31;
                float4 s4 = {0,0,0,0};
                const float* p = cxp + (((size_t)(pb_b0 + bsub) * NCH) * NC + pb_n) * KD + (k4 << 2);
                #pragma unroll
                for (int c2 = 0; c2 < NCH; ++c2) {
                    float4 v4 = *(const float4*)(p + (size_t)c2 * NC * KD);
                    s4.x += v4.x; s4.y += v4.y; s4.z += v4.z; s4.w += v4.w;
                }
                *(float4*)(cxs + (t >> 5) * KD + (k4 << 2)) = s4;
            }
            __syncthreads();

            // s[d] + squash (8 b's, 32 d's)
            const int bsub = t >> 5, d = t & 31;
            float s = 0.f;
            const float* crow = cxs + bsub * KD;
            for (int k = 0; k < KD; ++k) s += crow[k] * w_s[k * WSTR + d];
            float sn = s * s;
            #pragma unroll
            for (int off = 1; off < 32; off <<= 1) sn += __shfl_xor(sn, off, 64);
            const float vv = s * (sn / ((1.f + sn) * (sqrtf(sn) + 1e-8f)));

            if (final_) {
                out_g[((size_t)(pb_b0 + bsub) * NC + pb_n) * DC + d] = vv;
            } else {
                vs_s[bsub * DC + d] = vv;
                __syncthreads();
                // wv[k] = W[k,:].v for 8 b's; thread = (bg 0..1, k 0..127)
                const int k = t & 127, bg = t >> 7;
                #pragma unroll
                for (int q = 0; q < 4; ++q) {
                    const int bs = bg * 4 + q;
                    float a = 0.f;
                    #pragma unroll
                    for (int dd = 0; dd < DC; ++dd) a += w_s[k * WSTR + dd] * vs_s[bs * DC + dd];
                    wv_g[((size_t)(pb_b0 + bs) * NC + pb_n) * KD + k] = a;
                }
            }
        }

        if (!final_) gridbar(ctr, slot++);   // wv visible
    }
}

extern "C" void kernel_launch(void* const* d_in, const int* in_sizes, int n_in,
                              void* d_out, int out_size, void* d_ws, size_t ws_size,
                              hipStream_t stream) {
    const float* x  = (const float*)d_in[0];
    const float* W  = (const float*)d_in[1];
    const float* b0 = (const float*)d_in[2];
    float* out = (float*)d_out;

    float* cxp   = (float*)d_ws;                 // 8 MB
    float* wv    = cxp + CXP_SZ;                 // 1 MB
    float* bb_ws = wv + WV_SZ;                   // 4 MB
    unsigned* ctr = (unsigned*)(bb_ws + BB_SZ);  // 8 barrier slots

    hipMemsetAsync(ctr, 0, 8 * sizeof(unsigned), stream);
    capsAll<<<GBLK, NTHR, 0, stream>>>(x, W, b0, out, cxp, wv, bb_ws, ctr);
}